// Round 2
// 242.142 us; speedup vs baseline: 1.0346x; 1.0346x over previous
//
#include <hip/hip_runtime.h>

// MovementEmbeddingModule: bs=4, d=16, K=10, C=3, h=w=128
// out: (4, 60, 16, 128, 128) f32; out[b][k*6+c][d][y][x]
#define BS 4
#define DD 16
#define KK 10
#define CC 3
#define HH 128
#define WW 128

#define LROW 132    // 129 staged cols, padded to 132 (16B-multiple row stride)

using f4 = __attribute__((ext_vector_type(4))) float;

__global__ __launch_bounds__(256) void movement_embed_kernel(
    const float* __restrict__ kp_app,   // (4,1,10,2)
    const float* __restrict__ kp_vid,   // (4,16,10,2)
    const float* __restrict__ img,      // (4,3,128,128)
    float* __restrict__ out)
{
    // Wave-PRIVATE staging: wave w owns P[w][*][*][*]. No __syncthreads in the
    // kernel at all -- each wave stages the 3 source rows x 3 channels it
    // consumes, then a wave-level s_waitcnt lgkmcnt(0) orders write->read.
    // This decouples the 32 resident waves/CU so store issue stays uniform
    // (the old barrier made stores bursty: ~2.5 TB/s effective vs 6.7 peak).
    __shared__ __align__(16) float P[4][CC][3][LROW];   // 19,008 B

    const unsigned bi  = blockIdx.x;
    const unsigned sub = bi & 15u;          // 16 row-tiles (8 rows each) per (b,d,k)
    const unsigned bdk = bi >> 4;
    const unsigned k   = bdk % KK;
    const unsigned t2  = bdk / KK;
    const unsigned d   = t2 % DD;
    const unsigned b   = t2 / DD;
    const int tid  = (int)threadIdx.x;
    const int lane = tid & 63;
    const int wv   = tid >> 6;              // wave id 0..3

    // wave-uniform keypoint math (SGPR path)
    const float kvx  = kp_vid[((b*DD + d)*KK + k)*2 + 0];
    const float kvy  = kp_vid[((b*DD + d)*KK + k)*2 + 1];
    const float kv0x = kp_vid[((b*DD + 0)*KK + k)*2 + 0];
    const float kv0y = kp_vid[((b*DD + 0)*KK + k)*2 + 1];
    const float kax  = kp_app[(b*KK + k)*2 + 0];
    const float kay  = kp_app[(b*KK + k)*2 + 1];

    const float diffx = kvx - kv0x;     // exactly 0 at d==0
    const float diffy = kvy - kv0y;
    const float mx = diffx + kax;       // heatmap center
    const float my = diffy + kay;
    const float vdx = -diffx;           // kp_video_diff (diff-map consts + warp shift)
    const float vdy = -diffy;

    // Uniform bilinear decomposition: sample coord = pixel + c (step*(W-1)/2 == 1.0)
    const float cx = vdx * 63.5f;
    const float cy = vdy * 63.5f;
    const float fcx = floorf(cx);
    const float fcy = floorf(cy);
    const int icx = (int)fcx;
    const int icy = (int)fcy;
    const float wx1 = cx - fcx, wx0 = 1.0f - wx1;   // block-uniform weights
    const float wy1 = cy - fcy, wy0 = 1.0f - wy1;

    // Wave w computes output rows sub*8 + 2*wv + {0,1}; it needs source rows
    // R0 .. R0+2 (3 rows) of each channel.
    const int R0 = (int)(sub * 8u) + 2 * wv + icy;
    const float* imgb = img + (size_t)b * (CC*HH*WW);

    // ---- wave-private stage: 3ch x 3 rows x 129 cols (clamped addr + mask) ----
#pragma unroll
    for (int c = 0; c < CC; ++c) {
        const float* pc = imgb + c * (HH * WW);
#pragma unroll
        for (int ri = 0; ri < 3; ++ri) {
            const int  r   = R0 + ri;
            const bool rok = (unsigned)r < (unsigned)HH;
            const float* rp = pc + (size_t)min(max(r, 0), HH - 1) * WW;

            const int c0 = icx + lane;
            const int c1 = c0 + 64;
            float v0 = rp[min(max(c0, 0), WW - 1)];
            float v1 = rp[min(max(c1, 0), WW - 1)];
            v0 = (rok && (unsigned)c0 < (unsigned)WW) ? v0 : 0.0f;
            v1 = (rok && (unsigned)c1 < (unsigned)WW) ? v1 : 0.0f;
            P[wv][c][ri][lane]      = v0;
            P[wv][c][ri][lane + 64] = v1;
        }
    }
    // col-128 tail: 9 lanes, one per (c,ri) -- single divergent region
    if (lane < CC * 3) {
        const int  c   = lane / 3;
        const int  ri  = lane - c * 3;
        const int  r   = R0 + ri;
        const bool rok = (unsigned)r < (unsigned)HH;
        const float* rp = imgb + c * (HH * WW) + (size_t)min(max(r, 0), HH - 1) * WW;
        const int  c2  = icx + 128;
        float v2 = rp[min(max(c2, 0), WW - 1)];
        P[wv][c][ri][128] = (rok && (unsigned)c2 < (unsigned)WW) ? v2 : 0.0f;
    }

    // ---- compute (LDS-independent part first, to overlap the LDS wait) ----
    const int xg = lane & 31;       // float4 column
    const int lr = lane >> 5;       // local row within wave: 0/1
    const int x4 = xg * 4;
    const int y  = (int)(sub * 8u) + 2 * wv + lr;

    const float step = 2.0f / 127.0f;
    const float gy  = (float)y  * step - 1.0f;
    const float gx0 = (float)x4 * step - 1.0f;

    // heatmap: exp(-50*r^2(kp_mean)) - exp(-50*r^2(kp_app)); exact 0 at d==0
    const float dy1 = gy - my, dy0 = gy - kay;
    const float dy1sq = dy1 * dy1, dy0sq = dy0 * dy0;
    float hv[4];
#pragma unroll
    for (int j = 0; j < 4; ++j) {
        const float gx = gx0 + (float)j * step;
        const float dx1 = gx - mx, dx0 = gx - kax;
        hv[j] = __expf(-50.0f * (dx1 * dx1 + dy1sq))
              - __expf(-50.0f * (dx0 * dx0 + dy0sq));
    }

    // ---- stores: out[b][k*6+c][d][y][x] ----
    const size_t chs  = (size_t)DD * HH * WW;  // 262144
    const size_t base = ((((size_t)b * (KK * 6) + k * 6) * DD + d) * HH + y) * WW + (size_t)x4;

    // Issue the 3 LDS-independent channel stores NOW (overlaps staging latency)
    {
        f4 h; h.x = hv[0]; h.y = hv[1]; h.z = hv[2]; h.w = hv[3];
        *(f4*)(out + base) = h;
        f4 vx; vx.x = vdx; vx.y = vdx; vx.z = vdx; vx.w = vdx;
        *(f4*)(out + base + chs) = vx;
        f4 vy; vy.x = vdy; vy.y = vdy; vy.z = vdy; vy.w = vdy;
        *(f4*)(out + base + 2 * chs) = vy;
    }

    // wave-level LDS fence: all ds_writes by this wave complete before reads.
    // ("memory" clobber stops the compiler reordering LDS ops across it; HW
    // per-wave in-order issue + lgkmcnt(0) guarantees completion.)
    asm volatile("s_waitcnt lgkmcnt(0)" ::: "memory");

    // deformed: uniform-weight blend of shifted rows from this wave's LDS slab
#pragma unroll
    for (int c = 0; c < CC; ++c) {
        const float* row0 = &P[wv][c][lr][x4];
        const float* row1 = &P[wv][c][lr + 1][x4];
        const float4 A = *(const float4*)row0;
        const float  ea = row0[4];
        const float4 B = *(const float4*)row1;
        const float  eb = row1[4];
        const float h0x = wx0 * A.x + wx1 * A.y;
        const float h0y = wx0 * A.y + wx1 * A.z;
        const float h0z = wx0 * A.z + wx1 * A.w;
        const float h0w = wx0 * A.w + wx1 * ea;
        const float h1x = wx0 * B.x + wx1 * B.y;
        const float h1y = wx0 * B.y + wx1 * B.z;
        const float h1z = wx0 * B.z + wx1 * B.w;
        const float h1w = wx0 * B.w + wx1 * eb;
        f4 dv;
        dv.x = wy0 * h0x + wy1 * h1x;
        dv.y = wy0 * h0y + wy1 * h1y;
        dv.z = wy0 * h0z + wy1 * h1z;
        dv.w = wy0 * h0w + wy1 * h1w;
        *(f4*)(out + base + (size_t)(3 + c) * chs) = dv;
    }
}

extern "C" void kernel_launch(void* const* d_in, const int* in_sizes, int n_in,
                              void* d_out, int out_size, void* d_ws, size_t ws_size,
                              hipStream_t stream) {
    const float* kp_app = (const float*)d_in[0];   // (4,1,10,2)
    const float* kp_vid = (const float*)d_in[1];   // (4,16,10,2)
    const float* img    = (const float*)d_in[2];   // (4,3,1,128,128)
    float* out = (float*)d_out;                    // (4,60,16,128,128)

    const int nblocks = BS * DD * KK * 16;         // 10240
    movement_embed_kernel<<<nblocks, 256, 0, stream>>>(kp_app, kp_vid, img, out);
}